// Round 16
// baseline (900.843 us; speedup 1.0000x reference)
//
#include <hip/hip_runtime.h>
#include <stdint.h>

#define B_ROWS 2048
#define DIM    2048
#define FDICT  32768
#define KSEL   64
#define TOPC   96       // candidate list from bf16 GEMM
#define WLO    52       // bf16-certain ranks [0,52) keep bf16 values
#define WHI    80       // ranks [52,80) recomputed np-bit-exact (boundary window)
#define CAP    1536     // per-row candidate capacity (mean ~616 @ 2.35 sigma)
#define THRFAC 2.35f
#define WSAMPN (64 * DIM)   // Wenc sample count for sigma_w estimate

typedef __attribute__((ext_vector_type(8))) short bf16x8;
typedef __attribute__((ext_vector_type(4))) float f32x4;

__device__ __forceinline__ float bf16_to_f32(ushort u)
{
    return __uint_as_float(((uint32_t)u) << 16);
}

// ======================= init: zero counters =======================
__global__ __launch_bounds__(256) void zero_kernel(int* __restrict__ cand_cnt,
                                                   float* __restrict__ wsum)
{
    int i = blockIdx.x * 256 + threadIdx.x;
    if (i < B_ROWS) cand_cnt[i] = 0;
    if (i == 0) wsum[0] = 0.f;
}

// ======================= sigma_w estimate (sample 64 Wenc rows) ==============
__global__ __launch_bounds__(256) void wstat_kernel(
    const float* __restrict__ Wenc, float* __restrict__ wsum)
{
    __shared__ float red[256];
    const int tid = threadIdx.x;
    float s = 0.f;
    for (int i = blockIdx.x * 256 + tid; i < WSAMPN / 4; i += 8 * 256) {
        float4 w = ((const float4*)Wenc)[i];
        s += w.x * w.x + w.y * w.y + w.z * w.z + w.w * w.w;
    }
    red[tid] = s;
    __syncthreads();
    for (int o = 128; o > 0; o >>= 1) {
        if (tid < o) red[tid] += red[tid + o];
        __syncthreads();
    }
    if (tid == 0) atomicAdd(wsum, red[0]);
}

// ====== fused: per-row threshold T = f * sigma_w * ||x_row|| + x -> bf16 =====
__global__ __launch_bounds__(256) void rownorm_conv_kernel(
    const float* __restrict__ x, const float* __restrict__ wsum,
    float* __restrict__ T, ushort* __restrict__ x_bf16)
{
    __shared__ float red[256];
    const int row = blockIdx.x;
    const int tid = threadIdx.x;
    const float* xr = x + (size_t)row * DIM;
    float4 u = *(const float4*)(xr + tid * 8);
    float4 v = *(const float4*)(xr + tid * 8 + 4);
    float t[8] = {u.x, u.y, u.z, u.w, v.x, v.y, v.z, v.w};
    union { ushort s[8]; bf16x8 w; } o;
    float s = 0.f;
#pragma unroll
    for (int j = 0; j < 8; ++j) {
        s += t[j] * t[j];
        union { __bf16 h; ushort s; } cv;
        cv.h = (__bf16)t[j];
        o.s[j] = cv.s;
    }
    *(bf16x8*)(x_bf16 + (size_t)row * DIM + tid * 8) = o.w;
    red[tid] = s;
    __syncthreads();
    for (int off = 128; off > 0; off >>= 1) {
        if (tid < off) red[tid] += red[tid + off];
        __syncthreads();
    }
    if (tid == 0)
        T[row] = THRFAC * sqrtf(wsum[0] / (float)WSAMPN) * sqrtf(red[0]);
}

// -------- fp32 -> bf16 (RNE) streaming convert (Wenc) --------
__global__ __launch_bounds__(256) void conv_bf16_kernel(
    const float* __restrict__ src, ushort* __restrict__ dst)
{
    const size_t i = ((size_t)blockIdx.x * 256 + threadIdx.x) * 8;
    float4 u = *(const float4*)(src + i);
    float4 v = *(const float4*)(src + i + 4);
    union { ushort s[8]; bf16x8 w; } o;
    float t[8] = {u.x, u.y, u.z, u.w, v.x, v.y, v.z, v.w};
#pragma unroll
    for (int j = 0; j < 8; ++j) {
        union { __bf16 h; ushort s; } cv;
        cv.h = (__bf16)t[j];
        o.s[j] = cv.s;
    }
    *(bf16x8*)(dst + i) = o.w;
}

// ====== encode GEMM: 64x256 tile, 4 waves (1M x 4N), 64x64 out/wave =========
// Same proven 2-phase skeleton as r13 (T2 swizzle 0-conflict, counted vmcnt,
// T1 XCD swizzle) but 40KB LDS -> 4 blocks/CU = 4 independent barrier domains
// at 16 waves/CU: staggered blocks cover each other's stage+barrier stalls.
#define GM 64
#define GN 256
#define GK 32
#define NT (DIM / GK)        // 64 K-tiles

__device__ __forceinline__ void gload_lds16(const void* g, void* l)
{
    __builtin_amdgcn_global_load_lds(
        (const __attribute__((address_space(1))) void*)(uintptr_t)g,
        (__attribute__((address_space(3))) void*)(uint32_t)(uintptr_t)l,
        16, 0, 0);
}

__global__ __launch_bounds__(256, 4) void enc_gemm_cand(
    const ushort* __restrict__ A,    // x_bf16    [B_ROWS][DIM]
    const ushort* __restrict__ Bw,   // Wenc_bf16 [FDICT][DIM]
    const float* __restrict__ benc,
    const float* __restrict__ T,     // [B_ROWS] per-row threshold
    float* __restrict__ cand_val,    // [B_ROWS][CAP]
    int* __restrict__ cand_idx,      // [B_ROWS][CAP]
    int* __restrict__ cand_cnt)      // [B_ROWS]
{
    __shared__ __align__(16) ushort As[2][GM * GK];   // 2 x 4 KB
    __shared__ __align__(16) ushort Bs[2][GN * GK];   // 2 x 16 KB

    const int tid  = threadIdx.x;
    const int lane = tid & 63;
    const int wc   = tid >> 6;              // wave 0..3 = N-quadrant
    const int lr   = lane & 15, lg = lane >> 4;

    // T1: bijective XCD swizzle. 4096 blocks, 8 XCDs -> 512 each;
    // row-block fast (32) -> each XCD owns 16 whole 256-col W-panels.
    const int bid = blockIdx.x;
    const int nf  = (bid & 7) * 512 + (bid >> 3);
    const int row0 = (nf & 31) * GM;
    const int col0 = (nf >> 5) * GN;

    const ushort* aSrc = A  + (size_t)row0 * DIM;
    const ushort* bSrc = Bw + (size_t)col0 * DIM;

    f32x4 acc[4][4] = {};

    // Stage one K-tile (A 4KB + B 16KB): per thread 1 A + 4 B gload_lds.
    // LDS written linearly; source 8-elem block pre-swizzled (r10-verified):
    // LDS[r][b] = global[r][b ^ ((r>>1)&3)].
#define STAGE(bsel, kt)                                                        \
    {                                                                          \
        const int k0_ = (kt) * GK;                                             \
        {   /* A: 256 segments, 1 op/thread */                                 \
            const int q_  = tid;                                               \
            const int r_  = q_ >> 2;                                           \
            const int sb_ = (q_ & 3) ^ ((r_ >> 1) & 3);                        \
            gload_lds16(aSrc + (size_t)r_ * DIM + k0_ + sb_ * 8,               \
                        (char*)&As[bsel][0] + q_ * 16);                        \
        }                                                                      \
        _Pragma("unroll")                                                      \
        for (int i_ = 0; i_ < 4; ++i_) {   /* B: 1024 segments, 4 ops */       \
            const int q_  = tid + i_ * 256;                                    \
            const int r_  = q_ >> 2;                                           \
            const int sb_ = (q_ & 3) ^ ((r_ >> 1) & 3);                        \
            gload_lds16(bSrc + (size_t)r_ * DIM + k0_ + sb_ * 8,               \
                        (char*)&Bs[bsel][0] + q_ * 16);                        \
        }                                                                      \
    }

    STAGE(0, 0);
    int cur = 0;
    for (int t = 0; t < NT; ++t) {
        __builtin_amdgcn_s_barrier();
        if (t + 1 < NT) {
            STAGE(cur ^ 1, t + 1);
            // wait ONLY tile t's 5 loads (oldest); t+1's 5 stay in flight
            asm volatile("s_waitcnt vmcnt(5)" ::: "memory");
        } else {
            asm volatile("s_waitcnt vmcnt(0)" ::: "memory");
        }
        __builtin_amdgcn_s_barrier();        // tile t resident for all waves
        __builtin_amdgcn_sched_barrier(0);

        bf16x8 af[4], bfr[4];
#pragma unroll
        for (int mi = 0; mi < 4; ++mi) {
            const int R = mi * 16 + lr;
            af[mi] = *(const bf16x8*)(&As[cur][0] + R * GK + ((lg ^ ((R >> 1) & 3)) * 8));
        }
#pragma unroll
        for (int ni = 0; ni < 4; ++ni) {
            const int R = wc * 64 + ni * 16 + lr;
            bfr[ni] = *(const bf16x8*)(&Bs[cur][0] + R * GK + ((lg ^ ((R >> 1) & 3)) * 8));
        }
#pragma unroll
        for (int mi = 0; mi < 4; ++mi)
#pragma unroll
            for (int ni = 0; ni < 4; ++ni)
                acc[mi][ni] = __builtin_amdgcn_mfma_f32_16x16x32_bf16(
                    af[mi], bfr[ni], acc[mi][ni], 0, 0, 0);
        cur ^= 1;
    }

    float bias[4];
#pragma unroll
    for (int ni = 0; ni < 4; ++ni)
        bias[ni] = benc[col0 + wc * 64 + ni * 16 + lr];

    // C/D layout (verified r4): col = lane&15, row = (lane>>4)*4 + reg
#pragma unroll
    for (int mi = 0; mi < 4; ++mi) {
#pragma unroll
        for (int r = 0; r < 4; ++r) {
            const int rloc = mi * 16 + lg * 4 + r;
            const float t = T[row0 + rloc];
#pragma unroll
            for (int ni = 0; ni < 4; ++ni) {
                const float v = acc[mi][ni][r] + bias[ni];
                if (fabsf(v) >= t) {
                    const int grow = row0 + rloc;
                    const int gcol = col0 + wc * 64 + ni * 16 + lr;
                    int pos = atomicAdd(&cand_cnt[grow], 1);
                    if (pos < CAP) {
                        cand_val[(size_t)grow * CAP + pos] = v;
                        cand_idx[(size_t)grow * CAP + pos] = gcol;
                    }
                }
            }
        }
    }
#undef STAGE
}

// ============ exact radix select: candidates -> top-TOPC (idx AND bf16 val) ==
__global__ __launch_bounds__(256) void select_kernel(
    const float* __restrict__ cand_val,
    const int* __restrict__ cand_idx,
    const int* __restrict__ cand_cnt,
    float* __restrict__ run_val,
    int* __restrict__ run_idx)
{
    const int row = blockIdx.x;
    const int tid = threadIdx.x;

    __shared__ uint32_t ua[CAP];
    __shared__ float    va[CAP];
    __shared__ int      si[CAP];
    __shared__ int      hist[256];
    __shared__ uint32_t sh_prefix;
    __shared__ int      sh_cgt, c_out, c_eq;

    int cnt = cand_cnt[row];
    if (cnt > CAP) cnt = CAP;

    for (int j = tid; j < cnt; j += 256) {
        float v = cand_val[(size_t)row * CAP + j];
        va[j] = v;
        ua[j] = __float_as_uint(v) & 0x7fffffffu;
        si[j] = cand_idx[(size_t)row * CAP + j];
    }
    if (tid == 0) { sh_prefix = 0u; sh_cgt = 0; c_out = 0; c_eq = 0; }
    __syncthreads();

    if (cnt <= TOPC) {
        if (tid < TOPC) {
            run_idx[(size_t)row * TOPC + tid] = (tid < cnt) ? si[tid] : -1;
            run_val[(size_t)row * TOPC + tid] = (tid < cnt) ? va[tid] : 0.f;
        }
        return;
    }

    for (int p = 3; p >= 0; --p) {
        hist[tid] = 0;
        __syncthreads();
        const uint32_t mask = (p == 3) ? 0u : (0xffffffffu << ((p + 1) * 8));
        const uint32_t pref = sh_prefix;
        for (int j = tid; j < cnt; j += 256) {
            uint32_t u = ua[j];
            if ((u & mask) == pref)
                atomicAdd(&hist[(u >> (p * 8)) & 255], 1);
        }
        __syncthreads();
        if (tid == 0) {
            int cum = sh_cgt;
            int chosen = 0;
            for (int b = 255; b >= 0; --b) {
                int c = hist[b];
                if (cum + c >= TOPC) { chosen = b; break; }
                cum += c;
            }
            sh_prefix = sh_prefix | ((uint32_t)chosen << (p * 8));
            sh_cgt = cum;
        }
        __syncthreads();
    }

    const uint32_t uth = sh_prefix;
    for (int j = tid; j < cnt; j += 256) {
        if (ua[j] > uth) {
            int pos = atomicAdd(&c_out, 1);
            run_idx[(size_t)row * TOPC + pos] = si[j];
            run_val[(size_t)row * TOPC + pos] = va[j];
        }
    }
    __syncthreads();
    const int base = c_out;
    for (int j = tid; j < cnt; j += 256) {
        if (ua[j] == uth) {
            int e = atomicAdd(&c_eq, 1);
            int slot = base + e;
            if (slot < TOPC) {
                run_idx[(size_t)row * TOPC + slot] = si[j];
                run_val[(size_t)row * TOPC + slot] = va[j];
            }
        }
    }
}

// ===== windowed np-bit-exact refinement ======================================
// Rank 96 candidates by bf16-GEMM value (fp32 bits, idx tie-break). Ranks
// [0,WLO): certainly in top-64, keep bf16 value. Ranks [WLO,WHI): recompute
// np-exact (numpy SSE 4-chain, mul/add RNE, no fma, (a0+a2)+(a1+a3), +b_enc),
// rank window by exact bits, fill slots WLO..63. Edge margins >=16 ranks
// (~23 sigma of bf16 rank noise).
__global__ __launch_bounds__(256) void refine_np_kernel(
    const float* __restrict__ x,
    const float* __restrict__ Wenc,
    const float* __restrict__ benc,
    const float* __restrict__ run_val,
    const int* __restrict__ run_idx,
    float* __restrict__ sel_val,
    int* __restrict__ sel_idx)
{
    const int half = threadIdx.x >> 7;      // row within block (0..1)
    const int cid  = threadIdx.x & 127;     // candidate id (<TOPC active)
    const int row  = blockIdx.x * 2 + half;

    __shared__ __align__(16) float xs[2][DIM];
    __shared__ float cval[2][TOPC];
    __shared__ int   cidx[2][TOPC];
    __shared__ short brnk[2][TOPC];

    {
        const float4* src = (const float4*)(x + (size_t)blockIdx.x * 2 * DIM);
        for (int i = threadIdx.x; i < 2 * DIM / 4; i += 256)
            ((float4*)xs)[i] = src[i];
    }
    if (cid < TOPC) {
        cidx[half][cid] = run_idx[(size_t)row * TOPC + cid];
        cval[half][cid] = run_val[(size_t)row * TOPC + cid];
    }
    __syncthreads();

    // bf16-value ranking (deterministic: bits desc, idx asc)
    if (cid < TOPC) {
        const int f = cidx[half][cid];
        int rank = TOPC;
        if (f >= 0) {
            const uint32_t av = __float_as_uint(cval[half][cid]) & 0x7fffffffu;
            rank = 0;
            for (int u = 0; u < TOPC; ++u) {
                if (u == cid) continue;
                int fu = cidx[half][u];
                if (fu < 0) continue;
                uint32_t au = __float_as_uint(cval[half][u]) & 0x7fffffffu;
                if (au > av || (au == av && fu < f)) ++rank;
            }
        }
        brnk[half][cid] = (short)rank;
    }
    __syncthreads();

    // np-exact recompute, window ranks only (28/row)
    if (cid < TOPC) {
        const int f = cidx[half][cid];
        const int r = brnk[half][cid];
        if (f >= 0 && r >= WLO && r < WHI) {
            const float4* w4 = (const float4*)(Wenc + (size_t)f * DIM);
            const float4* x4 = (const float4*)xs[half];
            float a0 = 0.f, a1 = 0.f, a2 = 0.f, a3 = 0.f;
            float4 pa[8], pb[8];
#pragma unroll
            for (int u = 0; u < 8; ++u) pa[u] = w4[u];
            for (int t0 = 0; t0 < DIM / 4; t0 += 16) {
#pragma unroll
                for (int u = 0; u < 8; ++u) pb[u] = w4[t0 + 8 + u];
#pragma unroll
                for (int u = 0; u < 8; ++u) {
                    float4 xv = x4[t0 + u];
                    a0 = __fadd_rn(a0, __fmul_rn(xv.x, pa[u].x));
                    a1 = __fadd_rn(a1, __fmul_rn(xv.y, pa[u].y));
                    a2 = __fadd_rn(a2, __fmul_rn(xv.z, pa[u].z));
                    a3 = __fadd_rn(a3, __fmul_rn(xv.w, pa[u].w));
                }
                if (t0 + 16 < DIM / 4) {
#pragma unroll
                    for (int u = 0; u < 8; ++u) pa[u] = w4[t0 + 16 + u];
                }
#pragma unroll
                for (int u = 0; u < 8; ++u) {
                    float4 xv = x4[t0 + 8 + u];
                    a0 = __fadd_rn(a0, __fmul_rn(xv.x, pb[u].x));
                    a1 = __fadd_rn(a1, __fmul_rn(xv.y, pb[u].y));
                    a2 = __fadd_rn(a2, __fmul_rn(xv.z, pb[u].z));
                    a3 = __fadd_rn(a3, __fmul_rn(xv.w, pb[u].w));
                }
            }
            float v = __fadd_rn(__fadd_rn(a0, a2), __fadd_rn(a1, a3));
            cval[half][cid] = __fadd_rn(v, benc[f]);
        }
    }
    __syncthreads();

    if (cid < TOPC) {
        const int f = cidx[half][cid];
        if (f >= 0) {
            const int r = brnk[half][cid];
            if (r < WLO) {
                sel_val[(size_t)row * KSEL + r] = cval[half][cid];
                sel_idx[(size_t)row * KSEL + r] = f;
            } else if (r < WHI) {
                const uint32_t av = __float_as_uint(cval[half][cid]) & 0x7fffffffu;
                int wr = 0;
                for (int u = 0; u < TOPC; ++u) {
                    if (u == cid) continue;
                    int fu = cidx[half][u];
                    if (fu < 0) continue;
                    int ru = brnk[half][u];
                    if (ru < WLO || ru >= WHI) continue;
                    uint32_t au = __float_as_uint(cval[half][u]) & 0x7fffffffu;
                    if (au > av || (au == av && fu < f)) ++wr;
                }
                if (wr < KSEL - WLO) {
                    sel_val[(size_t)row * KSEL + WLO + wr] = cval[half][cid];
                    sel_idx[(size_t)row * KSEL + WLO + wr] = f;
                }
            }
        }
    }
}

// ================= decode: Wdec -> bf16 [F][D], one-pass gather ==============
__global__ __launch_bounds__(256) void transpose_wdec_bf16(
    const float* __restrict__ Wdec,   // [DIM][FDICT]
    ushort* __restrict__ WdecT)       // [FDICT][DIM] bf16
{
    __shared__ float t[64][65];
    const int f0 = blockIdx.x * 64;
    const int d0 = blockIdx.y * 64;
    const int tx = threadIdx.x & 63;
    const int ty = threadIdx.x >> 6;  // 0..3
#pragma unroll
    for (int r = 0; r < 16; ++r)
        t[ty * 16 + r][tx] = Wdec[(size_t)(d0 + ty * 16 + r) * FDICT + f0 + tx];
    __syncthreads();
#pragma unroll
    for (int r = 0; r < 16; ++r) {
        union { __bf16 h; ushort s; } cv;
        cv.h = (__bf16)t[tx][ty * 16 + r];
        WdecT[(size_t)(f0 + ty * 16 + r) * DIM + d0 + tx] = cv.s;
    }
}

__global__ __launch_bounds__(256) void decode_full_kernel(
    const ushort* __restrict__ WdecT,   // [FDICT][DIM] bf16
    const float* __restrict__ sel_val,
    const int* __restrict__ sel_idx,
    const float* __restrict__ bdec,
    float* __restrict__ out)
{
    const int row = blockIdx.x;
    const int tid = threadIdx.x;
    __shared__ float vv[KSEL];
    __shared__ int   ff[KSEL];
    if (tid < KSEL) {
        vv[tid] = sel_val[row * KSEL + tid];
        ff[tid] = sel_idx[row * KSEL + tid];
    }
    __syncthreads();
    const int d0 = tid * 8;
    float acc[8];
    {
        float4 b0 = *(const float4*)(bdec + d0);
        float4 b1 = *(const float4*)(bdec + d0 + 4);
        acc[0] = b0.x; acc[1] = b0.y; acc[2] = b0.z; acc[3] = b0.w;
        acc[4] = b1.x; acc[5] = b1.y; acc[6] = b1.z; acc[7] = b1.w;
    }
    for (int k = 0; k < KSEL; ++k) {
        const int f = ff[k];
        if ((unsigned)f >= (unsigned)FDICT) continue;   // poison-safety guard
        const float v = vv[k];
        union { ushort s[8]; bf16x8 w; } u;
        u.w = *(const bf16x8*)(WdecT + (size_t)f * DIM + d0);
#pragma unroll
        for (int j = 0; j < 8; ++j)
            acc[j] = fmaf(v, bf16_to_f32(u.s[j]), acc[j]);
    }
    float* orow = out + (size_t)row * DIM + d0;
    float4 o0 = {acc[0], acc[1], acc[2], acc[3]};
    float4 o1 = {acc[4], acc[5], acc[6], acc[7]};
    *(float4*)(orow + 0) = o0;
    *(float4*)(orow + 4) = o1;
}

// ======================= launch =======================
extern "C" void kernel_launch(void* const* d_in, const int* in_sizes, int n_in,
                              void* d_out, int out_size, void* d_ws, size_t ws_size,
                              hipStream_t stream)
{
    const float* x    = (const float*)d_in[0];
    const float* Wenc = (const float*)d_in[1];
    const float* benc = (const float*)d_in[2];
    const float* Wdec = (const float*)d_in[3];
    const float* bdec = (const float*)d_in[4];
    (void)in_sizes; (void)n_in; (void)out_size; (void)ws_size;
    float* out = (float*)d_out;

    char* ws = (char*)d_ws;
    size_t off = 0;
    float*  cand_val = (float*)(ws + off);  off += (size_t)B_ROWS * CAP * 4;   // 12.6 MB
    int*    cand_idx = (int*)(ws + off);    off += (size_t)B_ROWS * CAP * 4;   // 12.6 MB
    int*    cand_cnt = (int*)(ws + off);    off += (size_t)B_ROWS * 4;
    float*  Tthr     = (float*)(ws + off);  off += (size_t)B_ROWS * 4;
    float*  wsum     = (float*)(ws + off);  off += 256;
    ushort* x_bf16   = (ushort*)(ws + off); off += (size_t)B_ROWS * DIM * 2;   // 8 MB
    float*  run_val  = (float*)(ws + off);  off += (size_t)B_ROWS * TOPC * 4;
    int*    run_idx  = (int*)(ws + off);    off += (size_t)B_ROWS * TOPC * 4;
    float*  sel_val  = (float*)(ws + off);  off += (size_t)B_ROWS * KSEL * 4;
    int*    sel_idx  = (int*)(ws + off);    off += (size_t)B_ROWS * KSEL * 4;
    char*   big      = ws + off;            // 128 MB: wenc_bf16, then WdecT

    zero_kernel<<<(B_ROWS + 255) / 256, 256, 0, stream>>>(cand_cnt, wsum);
    wstat_kernel<<<8, 256, 0, stream>>>(Wenc, wsum);
    rownorm_conv_kernel<<<B_ROWS, 256, 0, stream>>>(x, wsum, Tthr, x_bf16);

    ushort* wenc_bf = (ushort*)big;
    conv_bf16_kernel<<<(int)(((size_t)FDICT * DIM) / (256 * 8)), 256, 0, stream>>>(
        Wenc, wenc_bf);
    enc_gemm_cand<<<(B_ROWS / GM) * (FDICT / GN), 256, 0, stream>>>(
        x_bf16, wenc_bf, benc, Tthr, cand_val, cand_idx, cand_cnt);

    select_kernel<<<B_ROWS, 256, 0, stream>>>(cand_val, cand_idx, cand_cnt,
                                              run_val, run_idx);
    refine_np_kernel<<<B_ROWS / 2, 256, 0, stream>>>(x, Wenc, benc,
                                                     run_val, run_idx,
                                                     sel_val, sel_idx);

    ushort* WdecT = (ushort*)big;   // reuse: encode phase done
    transpose_wdec_bf16<<<dim3(FDICT / 64, DIM / 64), 256, 0, stream>>>(Wdec, WdecT);
    decode_full_kernel<<<B_ROWS, 256, 0, stream>>>(WdecT, sel_val, sel_idx, bdec, out);
}

// Round 17
// 811.757 us; speedup vs baseline: 1.1097x; 1.1097x over previous
//
#include <hip/hip_runtime.h>
#include <stdint.h>

#define B_ROWS 2048
#define DIM    2048
#define FDICT  32768
#define KSEL   64
#define TOPC   96       // candidate list from bf16 GEMM
#define WLO    52       // bf16-certain ranks [0,52) keep bf16 values
#define WHI    80       // ranks [52,80) recomputed np-bit-exact (boundary window)
#define CAP    1536     // per-row candidate capacity (mean ~616 @ 2.35 sigma)
#define THRFAC 2.35f
#define WSAMPN (64 * DIM)   // Wenc sample count for sigma_w estimate

typedef __attribute__((ext_vector_type(8))) short bf16x8;
typedef __attribute__((ext_vector_type(4))) float f32x4;

__device__ __forceinline__ float bf16_to_f32(ushort u)
{
    return __uint_as_float(((uint32_t)u) << 16);
}

// ======================= init: zero counters =======================
__global__ __launch_bounds__(256) void zero_kernel(int* __restrict__ cand_cnt,
                                                   float* __restrict__ wsum)
{
    int i = blockIdx.x * 256 + threadIdx.x;
    if (i < B_ROWS) cand_cnt[i] = 0;
    if (i == 0) wsum[0] = 0.f;
}

// ======================= sigma_w estimate (sample 64 Wenc rows) ==============
__global__ __launch_bounds__(256) void wstat_kernel(
    const float* __restrict__ Wenc, float* __restrict__ wsum)
{
    __shared__ float red[256];
    const int tid = threadIdx.x;
    float s = 0.f;
    for (int i = blockIdx.x * 256 + tid; i < WSAMPN / 4; i += 8 * 256) {
        float4 w = ((const float4*)Wenc)[i];
        s += w.x * w.x + w.y * w.y + w.z * w.z + w.w * w.w;
    }
    red[tid] = s;
    __syncthreads();
    for (int o = 128; o > 0; o >>= 1) {
        if (tid < o) red[tid] += red[tid + o];
        __syncthreads();
    }
    if (tid == 0) atomicAdd(wsum, red[0]);
}

// ====== fused: per-row threshold T = f * sigma_w * ||x_row|| + x -> bf16 =====
__global__ __launch_bounds__(256) void rownorm_conv_kernel(
    const float* __restrict__ x, const float* __restrict__ wsum,
    float* __restrict__ T, ushort* __restrict__ x_bf16)
{
    __shared__ float red[256];
    const int row = blockIdx.x;
    const int tid = threadIdx.x;
    const float* xr = x + (size_t)row * DIM;
    float4 u = *(const float4*)(xr + tid * 8);
    float4 v = *(const float4*)(xr + tid * 8 + 4);
    float t[8] = {u.x, u.y, u.z, u.w, v.x, v.y, v.z, v.w};
    union { ushort s[8]; bf16x8 w; } o;
    float s = 0.f;
#pragma unroll
    for (int j = 0; j < 8; ++j) {
        s += t[j] * t[j];
        union { __bf16 h; ushort s; } cv;
        cv.h = (__bf16)t[j];
        o.s[j] = cv.s;
    }
    *(bf16x8*)(x_bf16 + (size_t)row * DIM + tid * 8) = o.w;
    red[tid] = s;
    __syncthreads();
    for (int off = 128; off > 0; off >>= 1) {
        if (tid < off) red[tid] += red[tid + off];
        __syncthreads();
    }
    if (tid == 0)
        T[row] = THRFAC * sqrtf(wsum[0] / (float)WSAMPN) * sqrtf(red[0]);
}

// -------- fp32 -> bf16 (RNE) streaming convert (Wenc) --------
__global__ __launch_bounds__(256) void conv_bf16_kernel(
    const float* __restrict__ src, ushort* __restrict__ dst)
{
    const size_t i = ((size_t)blockIdx.x * 256 + threadIdx.x) * 8;
    float4 u = *(const float4*)(src + i);
    float4 v = *(const float4*)(src + i + 4);
    union { ushort s[8]; bf16x8 w; } o;
    float t[8] = {u.x, u.y, u.z, u.w, v.x, v.y, v.z, v.w};
#pragma unroll
    for (int j = 0; j < 8; ++j) {
        union { __bf16 h; ushort s; } cv;
        cv.h = (__bf16)t[j];
        o.s[j] = cv.s;
    }
    *(bf16x8*)(dst + i) = o.w;
}

// ====== encode GEMM (r13 config, proven 397us): 128x256 tile, 8 waves x
// (64x64 out) = 64 acc regs -> 4 waves/SIMD. BK=32 dbuf, T2 swizzle
// (r10-verified 0-conflict), T4 counted vmcnt(3), T1 XCD swizzle.
#define GM 128
#define GN 256
#define GK 32
#define NT (DIM / GK)        // 64 K-tiles

__device__ __forceinline__ void gload_lds16(const void* g, void* l)
{
    __builtin_amdgcn_global_load_lds(
        (const __attribute__((address_space(1))) void*)(uintptr_t)g,
        (__attribute__((address_space(3))) void*)(uint32_t)(uintptr_t)l,
        16, 0, 0);
}

__global__ __launch_bounds__(512, 4) void enc_gemm_cand(
    const ushort* __restrict__ A,    // x_bf16    [B_ROWS][DIM]
    const ushort* __restrict__ Bw,   // Wenc_bf16 [FDICT][DIM]
    const float* __restrict__ benc,
    const float* __restrict__ T,     // [B_ROWS] per-row threshold
    float* __restrict__ cand_val,    // [B_ROWS][CAP]
    int* __restrict__ cand_idx,      // [B_ROWS][CAP]
    int* __restrict__ cand_cnt)      // [B_ROWS]
{
    __shared__ __align__(16) ushort As[2][GM * GK];   // 2 x 8 KB
    __shared__ __align__(16) ushort Bs[2][GN * GK];   // 2 x 16 KB

    const int tid  = threadIdx.x;
    const int lane = tid & 63;
    const int wv   = tid >> 6;              // 0..7
    const int wr   = wv >> 2, wc = wv & 3;  // wave grid 2M x 4N: 64x64 out/wave
    const int lr   = lane & 15, lg = lane >> 4;

    const int bid = blockIdx.x;
    const int nf  = (bid & 7) * 256 + (bid >> 3);
    const int row0 = (nf & 15) * GM;
    const int col0 = (nf >> 4) * GN;

    const ushort* aSrc = A  + (size_t)row0 * DIM;
    const ushort* bSrc = Bw + (size_t)col0 * DIM;

    f32x4 acc[4][4] = {};

#define STAGE(bsel, kt)                                                        \
    {                                                                          \
        const int k0_ = (kt) * GK;                                             \
        {   /* A: 512 segments, 1 op/thread */                                 \
            const int q_  = wv * 64 + lane;                                    \
            const int r_  = q_ >> 2;                                           \
            const int sb_ = (q_ & 3) ^ ((r_ >> 1) & 3);                        \
            gload_lds16(aSrc + (size_t)r_ * DIM + k0_ + sb_ * 8,               \
                        (char*)&As[bsel][0] + (wv * 64) * 16);                 \
        }                                                                      \
        _Pragma("unroll")                                                      \
        for (int i_ = 0; i_ < 2; ++i_) {   /* B: 1024 segments, 2 ops */       \
            const int q0_ = wv * 128 + i_ * 64;                                \
            const int q_  = q0_ + lane;                                        \
            const int r_  = q_ >> 2;                                           \
            const int sb_ = (q_ & 3) ^ ((r_ >> 1) & 3);                        \
            gload_lds16(bSrc + (size_t)r_ * DIM + k0_ + sb_ * 8,               \
                        (char*)&Bs[bsel][0] + q0_ * 16);                       \
        }                                                                      \
    }

    STAGE(0, 0);
    int cur = 0;
    for (int t = 0; t < NT; ++t) {
        __builtin_amdgcn_s_barrier();
        if (t + 1 < NT) {
            STAGE(cur ^ 1, t + 1);
            asm volatile("s_waitcnt vmcnt(3)" ::: "memory");
        } else {
            asm volatile("s_waitcnt vmcnt(0)" ::: "memory");
        }
        __builtin_amdgcn_s_barrier();
        __builtin_amdgcn_sched_barrier(0);

        bf16x8 af[4], bfr[4];
#pragma unroll
        for (int mi = 0; mi < 4; ++mi) {
            const int R = wr * 64 + mi * 16 + lr;
            af[mi] = *(const bf16x8*)(&As[cur][0] + R * GK + ((lg ^ ((R >> 1) & 3)) * 8));
        }
#pragma unroll
        for (int ni = 0; ni < 4; ++ni) {
            const int R = wc * 64 + ni * 16 + lr;
            bfr[ni] = *(const bf16x8*)(&Bs[cur][0] + R * GK + ((lg ^ ((R >> 1) & 3)) * 8));
        }
#pragma unroll
        for (int mi = 0; mi < 4; ++mi)
#pragma unroll
            for (int ni = 0; ni < 4; ++ni)
                acc[mi][ni] = __builtin_amdgcn_mfma_f32_16x16x32_bf16(
                    af[mi], bfr[ni], acc[mi][ni], 0, 0, 0);
        cur ^= 1;
    }

    float bias[4];
#pragma unroll
    for (int ni = 0; ni < 4; ++ni)
        bias[ni] = benc[col0 + wc * 64 + ni * 16 + lr];

    // C/D layout (verified r4): col = lane&15, row = (lane>>4)*4 + reg
#pragma unroll
    for (int mi = 0; mi < 4; ++mi) {
#pragma unroll
        for (int r = 0; r < 4; ++r) {
            const int rloc = wr * 64 + mi * 16 + lg * 4 + r;
            const float t = T[row0 + rloc];
#pragma unroll
            for (int ni = 0; ni < 4; ++ni) {
                const float v = acc[mi][ni][r] + bias[ni];
                if (fabsf(v) >= t) {
                    const int grow = row0 + rloc;
                    const int gcol = col0 + wc * 64 + ni * 16 + lr;
                    int pos = atomicAdd(&cand_cnt[grow], 1);
                    if (pos < CAP) {
                        cand_val[(size_t)grow * CAP + pos] = v;
                        cand_idx[(size_t)grow * CAP + pos] = gcol;
                    }
                }
            }
        }
    }
#undef STAGE
}

// ============ exact radix select: candidates -> top-TOPC (idx AND bf16 val) ==
__global__ __launch_bounds__(256) void select_kernel(
    const float* __restrict__ cand_val,
    const int* __restrict__ cand_idx,
    const int* __restrict__ cand_cnt,
    float* __restrict__ run_val,
    int* __restrict__ run_idx)
{
    const int row = blockIdx.x;
    const int tid = threadIdx.x;

    __shared__ uint32_t ua[CAP];
    __shared__ float    va[CAP];
    __shared__ int      si[CAP];
    __shared__ int      hist[256];
    __shared__ uint32_t sh_prefix;
    __shared__ int      sh_cgt, c_out, c_eq;

    int cnt = cand_cnt[row];
    if (cnt > CAP) cnt = CAP;

    for (int j = tid; j < cnt; j += 256) {
        float v = cand_val[(size_t)row * CAP + j];
        va[j] = v;
        ua[j] = __float_as_uint(v) & 0x7fffffffu;
        si[j] = cand_idx[(size_t)row * CAP + j];
    }
    if (tid == 0) { sh_prefix = 0u; sh_cgt = 0; c_out = 0; c_eq = 0; }
    __syncthreads();

    if (cnt <= TOPC) {
        if (tid < TOPC) {
            run_idx[(size_t)row * TOPC + tid] = (tid < cnt) ? si[tid] : -1;
            run_val[(size_t)row * TOPC + tid] = (tid < cnt) ? va[tid] : 0.f;
        }
        return;
    }

    for (int p = 3; p >= 0; --p) {
        hist[tid] = 0;
        __syncthreads();
        const uint32_t mask = (p == 3) ? 0u : (0xffffffffu << ((p + 1) * 8));
        const uint32_t pref = sh_prefix;
        for (int j = tid; j < cnt; j += 256) {
            uint32_t u = ua[j];
            if ((u & mask) == pref)
                atomicAdd(&hist[(u >> (p * 8)) & 255], 1);
        }
        __syncthreads();
        if (tid == 0) {
            int cum = sh_cgt;
            int chosen = 0;
            for (int b = 255; b >= 0; --b) {
                int c = hist[b];
                if (cum + c >= TOPC) { chosen = b; break; }
                cum += c;
            }
            sh_prefix = sh_prefix | ((uint32_t)chosen << (p * 8));
            sh_cgt = cum;
        }
        __syncthreads();
    }

    const uint32_t uth = sh_prefix;
    for (int j = tid; j < cnt; j += 256) {
        if (ua[j] > uth) {
            int pos = atomicAdd(&c_out, 1);
            run_idx[(size_t)row * TOPC + pos] = si[j];
            run_val[(size_t)row * TOPC + pos] = va[j];
        }
    }
    __syncthreads();
    const int base = c_out;
    for (int j = tid; j < cnt; j += 256) {
        if (ua[j] == uth) {
            int e = atomicAdd(&c_eq, 1);
            int slot = base + e;
            if (slot < TOPC) {
                run_idx[(size_t)row * TOPC + slot] = si[j];
                run_val[(size_t)row * TOPC + slot] = va[j];
            }
        }
    }
}

// ===== windowed np-bit-exact refinement ======================================
// Rank 96 candidates by bf16-GEMM value (fp32 bits, idx tie-break). Ranks
// [0,WLO): certainly in top-64, keep bf16 value. Ranks [WLO,WHI): recompute
// np-exact (numpy SSE 4-chain, mul/add RNE, no fma, (a0+a2)+(a1+a3), +b_enc),
// rank window by exact bits, fill slots WLO..63. Edge margins >=16 ranks
// (~23 sigma of bf16 rank noise).
__global__ __launch_bounds__(256) void refine_np_kernel(
    const float* __restrict__ x,
    const float* __restrict__ Wenc,
    const float* __restrict__ benc,
    const float* __restrict__ run_val,
    const int* __restrict__ run_idx,
    float* __restrict__ sel_val,
    int* __restrict__ sel_idx)
{
    const int half = threadIdx.x >> 7;      // row within block (0..1)
    const int cid  = threadIdx.x & 127;     // candidate id (<TOPC active)
    const int row  = blockIdx.x * 2 + half;

    __shared__ __align__(16) float xs[2][DIM];
    __shared__ float cval[2][TOPC];
    __shared__ int   cidx[2][TOPC];
    __shared__ short brnk[2][TOPC];

    {
        const float4* src = (const float4*)(x + (size_t)blockIdx.x * 2 * DIM);
        for (int i = threadIdx.x; i < 2 * DIM / 4; i += 256)
            ((float4*)xs)[i] = src[i];
    }
    if (cid < TOPC) {
        cidx[half][cid] = run_idx[(size_t)row * TOPC + cid];
        cval[half][cid] = run_val[(size_t)row * TOPC + cid];
    }
    __syncthreads();

    // bf16-value ranking (deterministic: bits desc, idx asc)
    if (cid < TOPC) {
        const int f = cidx[half][cid];
        int rank = TOPC;
        if (f >= 0) {
            const uint32_t av = __float_as_uint(cval[half][cid]) & 0x7fffffffu;
            rank = 0;
            for (int u = 0; u < TOPC; ++u) {
                if (u == cid) continue;
                int fu = cidx[half][u];
                if (fu < 0) continue;
                uint32_t au = __float_as_uint(cval[half][u]) & 0x7fffffffu;
                if (au > av || (au == av && fu < f)) ++rank;
            }
        }
        brnk[half][cid] = (short)rank;
    }
    __syncthreads();

    // np-exact recompute, window ranks only (28/row)
    if (cid < TOPC) {
        const int f = cidx[half][cid];
        const int r = brnk[half][cid];
        if (f >= 0 && r >= WLO && r < WHI) {
            const float4* w4 = (const float4*)(Wenc + (size_t)f * DIM);
            const float4* x4 = (const float4*)xs[half];
            float a0 = 0.f, a1 = 0.f, a2 = 0.f, a3 = 0.f;
            float4 pa[8], pb[8];
#pragma unroll
            for (int u = 0; u < 8; ++u) pa[u] = w4[u];
            for (int t0 = 0; t0 < DIM / 4; t0 += 16) {
#pragma unroll
                for (int u = 0; u < 8; ++u) pb[u] = w4[t0 + 8 + u];
#pragma unroll
                for (int u = 0; u < 8; ++u) {
                    float4 xv = x4[t0 + u];
                    a0 = __fadd_rn(a0, __fmul_rn(xv.x, pa[u].x));
                    a1 = __fadd_rn(a1, __fmul_rn(xv.y, pa[u].y));
                    a2 = __fadd_rn(a2, __fmul_rn(xv.z, pa[u].z));
                    a3 = __fadd_rn(a3, __fmul_rn(xv.w, pa[u].w));
                }
                if (t0 + 16 < DIM / 4) {
#pragma unroll
                    for (int u = 0; u < 8; ++u) pa[u] = w4[t0 + 16 + u];
                }
#pragma unroll
                for (int u = 0; u < 8; ++u) {
                    float4 xv = x4[t0 + 8 + u];
                    a0 = __fadd_rn(a0, __fmul_rn(xv.x, pb[u].x));
                    a1 = __fadd_rn(a1, __fmul_rn(xv.y, pb[u].y));
                    a2 = __fadd_rn(a2, __fmul_rn(xv.z, pb[u].z));
                    a3 = __fadd_rn(a3, __fmul_rn(xv.w, pb[u].w));
                }
            }
            float v = __fadd_rn(__fadd_rn(a0, a2), __fadd_rn(a1, a3));
            cval[half][cid] = __fadd_rn(v, benc[f]);
        }
    }
    __syncthreads();

    if (cid < TOPC) {
        const int f = cidx[half][cid];
        if (f >= 0) {
            const int r = brnk[half][cid];
            if (r < WLO) {
                sel_val[(size_t)row * KSEL + r] = cval[half][cid];
                sel_idx[(size_t)row * KSEL + r] = f;
            } else if (r < WHI) {
                const uint32_t av = __float_as_uint(cval[half][cid]) & 0x7fffffffu;
                int wr = 0;
                for (int u = 0; u < TOPC; ++u) {
                    if (u == cid) continue;
                    int fu = cidx[half][u];
                    if (fu < 0) continue;
                    int ru = brnk[half][u];
                    if (ru < WLO || ru >= WHI) continue;
                    uint32_t au = __float_as_uint(cval[half][u]) & 0x7fffffffu;
                    if (au > av || (au == av && fu < f)) ++wr;
                }
                if (wr < KSEL - WLO) {
                    sel_val[(size_t)row * KSEL + WLO + wr] = cval[half][cid];
                    sel_idx[(size_t)row * KSEL + WLO + wr] = f;
                }
            }
        }
    }
}

// ================= decode: Wdec -> bf16 [F][D], one-pass gather ==============
__global__ __launch_bounds__(256) void transpose_wdec_bf16(
    const float* __restrict__ Wdec,   // [DIM][FDICT]
    ushort* __restrict__ WdecT)       // [FDICT][DIM] bf16
{
    __shared__ float t[64][65];
    const int f0 = blockIdx.x * 64;
    const int d0 = blockIdx.y * 64;
    const int tx = threadIdx.x & 63;
    const int ty = threadIdx.x >> 6;  // 0..3
#pragma unroll
    for (int r = 0; r < 16; ++r)
        t[ty * 16 + r][tx] = Wdec[(size_t)(d0 + ty * 16 + r) * FDICT + f0 + tx];
    __syncthreads();
#pragma unroll
    for (int r = 0; r < 16; ++r) {
        union { __bf16 h; ushort s; } cv;
        cv.h = (__bf16)t[tx][ty * 16 + r];
        WdecT[(size_t)(f0 + ty * 16 + r) * DIM + d0 + tx] = cv.s;
    }
}

__global__ __launch_bounds__(256) void decode_full_kernel(
    const ushort* __restrict__ WdecT,   // [FDICT][DIM] bf16
    const float* __restrict__ sel_val,
    const int* __restrict__ sel_idx,
    const float* __restrict__ bdec,
    float* __restrict__ out)
{
    const int row = blockIdx.x;
    const int tid = threadIdx.x;
    __shared__ float vv[KSEL];
    __shared__ int   ff[KSEL];
    if (tid < KSEL) {
        vv[tid] = sel_val[row * KSEL + tid];
        ff[tid] = sel_idx[row * KSEL + tid];
    }
    __syncthreads();
    const int d0 = tid * 8;
    float acc[8];
    {
        float4 b0 = *(const float4*)(bdec + d0);
        float4 b1 = *(const float4*)(bdec + d0 + 4);
        acc[0] = b0.x; acc[1] = b0.y; acc[2] = b0.z; acc[3] = b0.w;
        acc[4] = b1.x; acc[5] = b1.y; acc[6] = b1.z; acc[7] = b1.w;
    }
    for (int k = 0; k < KSEL; ++k) {
        const int f = ff[k];
        if ((unsigned)f >= (unsigned)FDICT) continue;   // poison-safety guard
        const float v = vv[k];
        union { ushort s[8]; bf16x8 w; } u;
        u.w = *(const bf16x8*)(WdecT + (size_t)f * DIM + d0);
#pragma unroll
        for (int j = 0; j < 8; ++j)
            acc[j] = fmaf(v, bf16_to_f32(u.s[j]), acc[j]);
    }
    float* orow = out + (size_t)row * DIM + d0;
    float4 o0 = {acc[0], acc[1], acc[2], acc[3]};
    float4 o1 = {acc[4], acc[5], acc[6], acc[7]};
    *(float4*)(orow + 0) = o0;
    *(float4*)(orow + 4) = o1;
}

// ======================= launch =======================
extern "C" void kernel_launch(void* const* d_in, const int* in_sizes, int n_in,
                              void* d_out, int out_size, void* d_ws, size_t ws_size,
                              hipStream_t stream)
{
    const float* x    = (const float*)d_in[0];
    const float* Wenc = (const float*)d_in[1];
    const float* benc = (const float*)d_in[2];
    const float* Wdec = (const float*)d_in[3];
    const float* bdec = (const float*)d_in[4];
    (void)in_sizes; (void)n_in; (void)out_size; (void)ws_size;
    float* out = (float*)d_out;

    char* ws = (char*)d_ws;
    size_t off = 0;
    float*  cand_val = (float*)(ws + off);  off += (size_t)B_ROWS * CAP * 4;   // 12.6 MB
    int*    cand_idx = (int*)(ws + off);    off += (size_t)B_ROWS * CAP * 4;   // 12.6 MB
    int*    cand_cnt = (int*)(ws + off);    off += (size_t)B_ROWS * 4;
    float*  Tthr     = (float*)(ws + off);  off += (size_t)B_ROWS * 4;
    float*  wsum     = (float*)(ws + off);  off += 256;
    ushort* x_bf16   = (ushort*)(ws + off); off += (size_t)B_ROWS * DIM * 2;   // 8 MB
    float*  run_val  = (float*)(ws + off);  off += (size_t)B_ROWS * TOPC * 4;
    int*    run_idx  = (int*)(ws + off);    off += (size_t)B_ROWS * TOPC * 4;
    float*  sel_val  = (float*)(ws + off);  off += (size_t)B_ROWS * KSEL * 4;
    int*    sel_idx  = (int*)(ws + off);    off += (size_t)B_ROWS * KSEL * 4;
    char*   big      = ws + off;            // 128 MB: wenc_bf16, then WdecT

    zero_kernel<<<(B_ROWS + 255) / 256, 256, 0, stream>>>(cand_cnt, wsum);
    wstat_kernel<<<8, 256, 0, stream>>>(Wenc, wsum);
    rownorm_conv_kernel<<<B_ROWS, 256, 0, stream>>>(x, wsum, Tthr, x_bf16);

    ushort* wenc_bf = (ushort*)big;
    conv_bf16_kernel<<<(int)(((size_t)FDICT * DIM) / (256 * 8)), 256, 0, stream>>>(
        Wenc, wenc_bf);
    enc_gemm_cand<<<(B_ROWS / GM) * (FDICT / GN), 512, 0, stream>>>(
        x_bf16, wenc_bf, benc, Tthr, cand_val, cand_idx, cand_cnt);

    select_kernel<<<B_ROWS, 256, 0, stream>>>(cand_val, cand_idx, cand_cnt,
                                              run_val, run_idx);
    refine_np_kernel<<<B_ROWS / 2, 256, 0, stream>>>(x, Wenc, benc,
                                                     run_val, run_idx,
                                                     sel_val, sel_idx);

    ushort* WdecT = (ushort*)big;   // reuse: encode phase done
    transpose_wdec_bf16<<<dim3(FDICT / 64, DIM / 64), 256, 0, stream>>>(Wdec, WdecT);
    decode_full_kernel<<<B_ROWS, 256, 0, stream>>>(WdecT, sel_val, sel_idx, bdec, out);
}

// Round 18
// 795.555 us; speedup vs baseline: 1.1323x; 1.0204x over previous
//
#include <hip/hip_runtime.h>
#include <stdint.h>

#define B_ROWS 2048
#define DIM    2048
#define FDICT  32768
#define KSEL   64
#define TOPC   96       // candidate list from bf16 GEMM
#define WLO    56       // bf16-certain ranks [0,56) keep bf16 values
#define WHI    76       // ranks [56,76) recomputed np-bit-exact (boundary window)
#define CAP    1536     // per-row candidate capacity (mean ~616 @ 2.35 sigma)
#define THRFAC 2.35f
#define WSAMPN (64 * DIM)   // Wenc sample count for sigma_w estimate

typedef __attribute__((ext_vector_type(8))) short bf16x8;
typedef __attribute__((ext_vector_type(4))) float f32x4;

__device__ __forceinline__ float bf16_to_f32(ushort u)
{
    return __uint_as_float(((uint32_t)u) << 16);
}

// ======================= init: zero counters =======================
__global__ __launch_bounds__(256) void zero_kernel(int* __restrict__ cand_cnt,
                                                   float* __restrict__ wsum)
{
    int i = blockIdx.x * 256 + threadIdx.x;
    if (i < B_ROWS) cand_cnt[i] = 0;
    if (i == 0) wsum[0] = 0.f;
}

// ======================= sigma_w estimate (sample 64 Wenc rows) ==============
__global__ __launch_bounds__(256) void wstat_kernel(
    const float* __restrict__ Wenc, float* __restrict__ wsum)
{
    __shared__ float red[256];
    const int tid = threadIdx.x;
    float s = 0.f;
    for (int i = blockIdx.x * 256 + tid; i < WSAMPN / 4; i += 8 * 256) {
        float4 w = ((const float4*)Wenc)[i];
        s += w.x * w.x + w.y * w.y + w.z * w.z + w.w * w.w;
    }
    red[tid] = s;
    __syncthreads();
    for (int o = 128; o > 0; o >>= 1) {
        if (tid < o) red[tid] += red[tid + o];
        __syncthreads();
    }
    if (tid == 0) atomicAdd(wsum, red[0]);
}

// ====== fused: per-row threshold T = f * sigma_w * ||x_row|| + x -> bf16 =====
__global__ __launch_bounds__(256) void rownorm_conv_kernel(
    const float* __restrict__ x, const float* __restrict__ wsum,
    float* __restrict__ T, ushort* __restrict__ x_bf16)
{
    __shared__ float red[256];
    const int row = blockIdx.x;
    const int tid = threadIdx.x;
    const float* xr = x + (size_t)row * DIM;
    float4 u = *(const float4*)(xr + tid * 8);
    float4 v = *(const float4*)(xr + tid * 8 + 4);
    float t[8] = {u.x, u.y, u.z, u.w, v.x, v.y, v.z, v.w};
    union { ushort s[8]; bf16x8 w; } o;
    float s = 0.f;
#pragma unroll
    for (int j = 0; j < 8; ++j) {
        s += t[j] * t[j];
        union { __bf16 h; ushort s; } cv;
        cv.h = (__bf16)t[j];
        o.s[j] = cv.s;
    }
    *(bf16x8*)(x_bf16 + (size_t)row * DIM + tid * 8) = o.w;
    red[tid] = s;
    __syncthreads();
    for (int off = 128; off > 0; off >>= 1) {
        if (tid < off) red[tid] += red[tid + off];
        __syncthreads();
    }
    if (tid == 0)
        T[row] = THRFAC * sqrtf(wsum[0] / (float)WSAMPN) * sqrtf(red[0]);
}

// -------- fp32 -> bf16 (RNE) streaming convert (Wenc) --------
__global__ __launch_bounds__(256) void conv_bf16_kernel(
    const float* __restrict__ src, ushort* __restrict__ dst)
{
    const size_t i = ((size_t)blockIdx.x * 256 + threadIdx.x) * 8;
    float4 u = *(const float4*)(src + i);
    float4 v = *(const float4*)(src + i + 4);
    union { ushort s[8]; bf16x8 w; } o;
    float t[8] = {u.x, u.y, u.z, u.w, v.x, v.y, v.z, v.w};
#pragma unroll
    for (int j = 0; j < 8; ++j) {
        union { __bf16 h; ushort s; } cv;
        cv.h = (__bf16)t[j];
        o.s[j] = cv.s;
    }
    *(bf16x8*)(dst + i) = o.w;
}

// ====== encode GEMM: r13 geometry (128x256, 8 waves, 64x64/wave) + r12's
// triple-buffer stage-2-ahead schedule. LDS 72KB; occupancy reg-bound at
// 2 blocks/CU either way, so deeper prefetch is free. T2 swizzle
// (r10-verified 0-conflict), counted vmcnt(3), T1 XCD swizzle.
#define GM 128
#define GN 256
#define GK 32
#define NT (DIM / GK)        // 64 K-tiles

__device__ __forceinline__ void gload_lds16(const void* g, void* l)
{
    __builtin_amdgcn_global_load_lds(
        (const __attribute__((address_space(1))) void*)(uintptr_t)g,
        (__attribute__((address_space(3))) void*)(uint32_t)(uintptr_t)l,
        16, 0, 0);
}

__global__ __launch_bounds__(512, 4) void enc_gemm_cand(
    const ushort* __restrict__ A,    // x_bf16    [B_ROWS][DIM]
    const ushort* __restrict__ Bw,   // Wenc_bf16 [FDICT][DIM]
    const float* __restrict__ benc,
    const float* __restrict__ T,     // [B_ROWS] per-row threshold
    float* __restrict__ cand_val,    // [B_ROWS][CAP]
    int* __restrict__ cand_idx,      // [B_ROWS][CAP]
    int* __restrict__ cand_cnt)      // [B_ROWS]
{
    __shared__ __align__(16) ushort As[3][GM * GK];   // 3 x 8 KB
    __shared__ __align__(16) ushort Bs[3][GN * GK];   // 3 x 16 KB

    const int tid  = threadIdx.x;
    const int lane = tid & 63;
    const int wv   = tid >> 6;              // 0..7
    const int wr   = wv >> 2, wc = wv & 3;  // wave grid 2M x 4N: 64x64 out/wave
    const int lr   = lane & 15, lg = lane >> 4;

    const int bid = blockIdx.x;
    const int nf  = (bid & 7) * 256 + (bid >> 3);
    const int row0 = (nf & 15) * GM;
    const int col0 = (nf >> 4) * GN;

    const ushort* aSrc = A  + (size_t)row0 * DIM;
    const ushort* bSrc = Bw + (size_t)col0 * DIM;

    f32x4 acc[4][4] = {};

    // Stage one K-tile (A 8KB + B 16KB): per thread 1 A + 2 B gload_lds.
    // LDS written linearly; source 8-elem block pre-swizzled (r10-verified):
    // LDS[r][b] = global[r][b ^ ((r>>1)&3)].
#define STAGE(bsel, kt)                                                        \
    {                                                                          \
        const int k0_ = (kt) * GK;                                             \
        {   /* A: 512 segments, 1 op/thread */                                 \
            const int q_  = wv * 64 + lane;                                    \
            const int r_  = q_ >> 2;                                           \
            const int sb_ = (q_ & 3) ^ ((r_ >> 1) & 3);                        \
            gload_lds16(aSrc + (size_t)r_ * DIM + k0_ + sb_ * 8,               \
                        (char*)&As[bsel][0] + (wv * 64) * 16);                 \
        }                                                                      \
        _Pragma("unroll")                                                      \
        for (int i_ = 0; i_ < 2; ++i_) {   /* B: 1024 segments, 2 ops */       \
            const int q0_ = wv * 128 + i_ * 64;                                \
            const int q_  = q0_ + lane;                                        \
            const int r_  = q_ >> 2;                                           \
            const int sb_ = (q_ & 3) ^ ((r_ >> 1) & 3);                        \
            gload_lds16(bSrc + (size_t)r_ * DIM + k0_ + sb_ * 8,               \
                        (char*)&Bs[bsel][0] + q0_ * 16);                       \
        }                                                                      \
    }

    // Prologue: tiles 0,1 staged; wait tile 0 (oldest 3 of 6), tile 1 in flight.
    STAGE(0, 0);
    STAGE(1, 1);
    asm volatile("s_waitcnt vmcnt(3)" ::: "memory");
    __builtin_amdgcn_s_barrier();
    __builtin_amdgcn_sched_barrier(0);

    for (int t = 0; t < NT; ++t) {
        const int s = t % 3;
        // stage tile t+2 into slot (t+2)%3 == (t-1)%3: its last reads finished
        // before barrier(t-1); loads get a full iteration to land.
        if (t + 2 < NT) STAGE((t + 2) % 3, t + 2);

        bf16x8 af[4], bfr[4];
#pragma unroll
        for (int mi = 0; mi < 4; ++mi) {
            const int R = wr * 64 + mi * 16 + lr;
            af[mi] = *(const bf16x8*)(&As[s][0] + R * GK + ((lg ^ ((R >> 1) & 3)) * 8));
        }
#pragma unroll
        for (int ni = 0; ni < 4; ++ni) {
            const int R = wc * 64 + ni * 16 + lr;
            bfr[ni] = *(const bf16x8*)(&Bs[s][0] + R * GK + ((lg ^ ((R >> 1) & 3)) * 8));
        }
#pragma unroll
        for (int mi = 0; mi < 4; ++mi)
#pragma unroll
            for (int ni = 0; ni < 4; ++ni)
                acc[mi][ni] = __builtin_amdgcn_mfma_f32_16x16x32_bf16(
                    af[mi], bfr[ni], acc[mi][ni], 0, 0, 0);

        // drain tile t+1's 3 loads (t+2's 3 stay in flight); never 0 mid-loop
        if (t + 2 < NT)
            asm volatile("s_waitcnt vmcnt(3)" ::: "memory");
        else
            asm volatile("s_waitcnt vmcnt(0)" ::: "memory");
        if (t + 1 < NT)
            __builtin_amdgcn_s_barrier();
        __builtin_amdgcn_sched_barrier(0);
    }

    float bias[4];
#pragma unroll
    for (int ni = 0; ni < 4; ++ni)
        bias[ni] = benc[col0 + wc * 64 + ni * 16 + lr];

    // C/D layout (verified r4): col = lane&15, row = (lane>>4)*4 + reg
#pragma unroll
    for (int mi = 0; mi < 4; ++mi) {
#pragma unroll
        for (int r = 0; r < 4; ++r) {
            const int rloc = wr * 64 + mi * 16 + lg * 4 + r;
            const float t = T[row0 + rloc];
#pragma unroll
            for (int ni = 0; ni < 4; ++ni) {
                const float v = acc[mi][ni][r] + bias[ni];
                if (fabsf(v) >= t) {
                    const int grow = row0 + rloc;
                    const int gcol = col0 + wc * 64 + ni * 16 + lr;
                    int pos = atomicAdd(&cand_cnt[grow], 1);
                    if (pos < CAP) {
                        cand_val[(size_t)grow * CAP + pos] = v;
                        cand_idx[(size_t)grow * CAP + pos] = gcol;
                    }
                }
            }
        }
    }
#undef STAGE
}

// ============ exact radix select: candidates -> top-TOPC (idx AND bf16 val) ==
__global__ __launch_bounds__(256) void select_kernel(
    const float* __restrict__ cand_val,
    const int* __restrict__ cand_idx,
    const int* __restrict__ cand_cnt,
    float* __restrict__ run_val,
    int* __restrict__ run_idx)
{
    const int row = blockIdx.x;
    const int tid = threadIdx.x;

    __shared__ uint32_t ua[CAP];
    __shared__ float    va[CAP];
    __shared__ int      si[CAP];
    __shared__ int      hist[256];
    __shared__ uint32_t sh_prefix;
    __shared__ int      sh_cgt, c_out, c_eq;

    int cnt = cand_cnt[row];
    if (cnt > CAP) cnt = CAP;

    for (int j = tid; j < cnt; j += 256) {
        float v = cand_val[(size_t)row * CAP + j];
        va[j] = v;
        ua[j] = __float_as_uint(v) & 0x7fffffffu;
        si[j] = cand_idx[(size_t)row * CAP + j];
    }
    if (tid == 0) { sh_prefix = 0u; sh_cgt = 0; c_out = 0; c_eq = 0; }
    __syncthreads();

    if (cnt <= TOPC) {
        if (tid < TOPC) {
            run_idx[(size_t)row * TOPC + tid] = (tid < cnt) ? si[tid] : -1;
            run_val[(size_t)row * TOPC + tid] = (tid < cnt) ? va[tid] : 0.f;
        }
        return;
    }

    for (int p = 3; p >= 0; --p) {
        hist[tid] = 0;
        __syncthreads();
        const uint32_t mask = (p == 3) ? 0u : (0xffffffffu << ((p + 1) * 8));
        const uint32_t pref = sh_prefix;
        for (int j = tid; j < cnt; j += 256) {
            uint32_t u = ua[j];
            if ((u & mask) == pref)
                atomicAdd(&hist[(u >> (p * 8)) & 255], 1);
        }
        __syncthreads();
        if (tid == 0) {
            int cum = sh_cgt;
            int chosen = 0;
            for (int b = 255; b >= 0; --b) {
                int c = hist[b];
                if (cum + c >= TOPC) { chosen = b; break; }
                cum += c;
            }
            sh_prefix = sh_prefix | ((uint32_t)chosen << (p * 8));
            sh_cgt = cum;
        }
        __syncthreads();
    }

    const uint32_t uth = sh_prefix;
    for (int j = tid; j < cnt; j += 256) {
        if (ua[j] > uth) {
            int pos = atomicAdd(&c_out, 1);
            run_idx[(size_t)row * TOPC + pos] = si[j];
            run_val[(size_t)row * TOPC + pos] = va[j];
        }
    }
    __syncthreads();
    const int base = c_out;
    for (int j = tid; j < cnt; j += 256) {
        if (ua[j] == uth) {
            int e = atomicAdd(&c_eq, 1);
            int slot = base + e;
            if (slot < TOPC) {
                run_idx[(size_t)row * TOPC + slot] = si[j];
                run_val[(size_t)row * TOPC + slot] = va[j];
            }
        }
    }
}

// ===== windowed np-bit-exact refinement ======================================
// Rank 96 candidates by bf16-GEMM value (fp32 bits, idx tie-break). Ranks
// [0,WLO): certainly in top-64, keep bf16 value. Ranks [WLO,WHI): recompute
// np-exact (numpy SSE 4-chain, mul/add RNE, no fma, (a0+a2)+(a1+a3), +b_enc),
// rank window by exact bits, fill slots WLO..63. Edge margins >= 8 ranks
// (~11 sigma of bf16 rank noise, sigma ~0.7 ranks).
__global__ __launch_bounds__(256) void refine_np_kernel(
    const float* __restrict__ x,
    const float* __restrict__ Wenc,
    const float* __restrict__ benc,
    const float* __restrict__ run_val,
    const int* __restrict__ run_idx,
    float* __restrict__ sel_val,
    int* __restrict__ sel_idx)
{
    const int half = threadIdx.x >> 7;      // row within block (0..1)
    const int cid  = threadIdx.x & 127;     // candidate id (<TOPC active)
    const int row  = blockIdx.x * 2 + half;

    __shared__ __align__(16) float xs[2][DIM];
    __shared__ float cval[2][TOPC];
    __shared__ int   cidx[2][TOPC];
    __shared__ short brnk[2][TOPC];

    {
        const float4* src = (const float4*)(x + (size_t)blockIdx.x * 2 * DIM);
        for (int i = threadIdx.x; i < 2 * DIM / 4; i += 256)
            ((float4*)xs)[i] = src[i];
    }
    if (cid < TOPC) {
        cidx[half][cid] = run_idx[(size_t)row * TOPC + cid];
        cval[half][cid] = run_val[(size_t)row * TOPC + cid];
    }
    __syncthreads();

    // bf16-value ranking (deterministic: bits desc, idx asc)
    if (cid < TOPC) {
        const int f = cidx[half][cid];
        int rank = TOPC;
        if (f >= 0) {
            const uint32_t av = __float_as_uint(cval[half][cid]) & 0x7fffffffu;
            rank = 0;
            for (int u = 0; u < TOPC; ++u) {
                if (u == cid) continue;
                int fu = cidx[half][u];
                if (fu < 0) continue;
                uint32_t au = __float_as_uint(cval[half][u]) & 0x7fffffffu;
                if (au > av || (au == av && fu < f)) ++rank;
            }
        }
        brnk[half][cid] = (short)rank;
    }
    __syncthreads();

    // np-exact recompute, window ranks only (20/row)
    if (cid < TOPC) {
        const int f = cidx[half][cid];
        const int r = brnk[half][cid];
        if (f >= 0 && r >= WLO && r < WHI) {
            const float4* w4 = (const float4*)(Wenc + (size_t)f * DIM);
            const float4* x4 = (const float4*)xs[half];
            float a0 = 0.f, a1 = 0.f, a2 = 0.f, a3 = 0.f;
            float4 pa[8], pb[8];
#pragma unroll
            for (int u = 0; u < 8; ++u) pa[u] = w4[u];
            for (int t0 = 0; t0 < DIM / 4; t0 += 16) {
#pragma unroll
                for (int u = 0; u < 8; ++u) pb[u] = w4[t0 + 8 + u];
#pragma unroll
                for (int u = 0; u < 8; ++u) {
                    float4 xv = x4[t0 + u];
                    a0 = __fadd_rn(a0, __fmul_rn(xv.x, pa[u].x));
                    a1 = __fadd_rn(a1, __fmul_rn(xv.y, pa[u].y));
                    a2 = __fadd_rn(a2, __fmul_rn(xv.z, pa[u].z));
                    a3 = __fadd_rn(a3, __fmul_rn(xv.w, pa[u].w));
                }
                if (t0 + 16 < DIM / 4) {
#pragma unroll
                    for (int u = 0; u < 8; ++u) pa[u] = w4[t0 + 16 + u];
                }
#pragma unroll
                for (int u = 0; u < 8; ++u) {
                    float4 xv = x4[t0 + 8 + u];
                    a0 = __fadd_rn(a0, __fmul_rn(xv.x, pb[u].x));
                    a1 = __fadd_rn(a1, __fmul_rn(xv.y, pb[u].y));
                    a2 = __fadd_rn(a2, __fmul_rn(xv.z, pb[u].z));
                    a3 = __fadd_rn(a3, __fmul_rn(xv.w, pb[u].w));
                }
            }
            float v = __fadd_rn(__fadd_rn(a0, a2), __fadd_rn(a1, a3));
            cval[half][cid] = __fadd_rn(v, benc[f]);
        }
    }
    __syncthreads();

    if (cid < TOPC) {
        const int f = cidx[half][cid];
        if (f >= 0) {
            const int r = brnk[half][cid];
            if (r < WLO) {
                sel_val[(size_t)row * KSEL + r] = cval[half][cid];
                sel_idx[(size_t)row * KSEL + r] = f;
            } else if (r < WHI) {
                const uint32_t av = __float_as_uint(cval[half][cid]) & 0x7fffffffu;
                int wr = 0;
                for (int u = 0; u < TOPC; ++u) {
                    if (u == cid) continue;
                    int fu = cidx[half][u];
                    if (fu < 0) continue;
                    int ru = brnk[half][u];
                    if (ru < WLO || ru >= WHI) continue;
                    uint32_t au = __float_as_uint(cval[half][u]) & 0x7fffffffu;
                    if (au > av || (au == av && fu < f)) ++wr;
                }
                if (wr < KSEL - WLO) {
                    sel_val[(size_t)row * KSEL + WLO + wr] = cval[half][cid];
                    sel_idx[(size_t)row * KSEL + WLO + wr] = f;
                }
            }
        }
    }
}

// ================= decode: Wdec -> bf16 [F][D], one-pass gather ==============
__global__ __launch_bounds__(256) void transpose_wdec_bf16(
    const float* __restrict__ Wdec,   // [DIM][FDICT]
    ushort* __restrict__ WdecT)       // [FDICT][DIM] bf16
{
    __shared__ float t[64][65];
    const int f0 = blockIdx.x * 64;
    const int d0 = blockIdx.y * 64;
    const int tx = threadIdx.x & 63;
    const int ty = threadIdx.x >> 6;  // 0..3
#pragma unroll
    for (int r = 0; r < 16; ++r)
        t[ty * 16 + r][tx] = Wdec[(size_t)(d0 + ty * 16 + r) * FDICT + f0 + tx];
    __syncthreads();
#pragma unroll
    for (int r = 0; r < 16; ++r) {
        union { __bf16 h; ushort s; } cv;
        cv.h = (__bf16)t[tx][ty * 16 + r];
        WdecT[(size_t)(f0 + ty * 16 + r) * DIM + d0 + tx] = cv.s;
    }
}

__global__ __launch_bounds__(256) void decode_full_kernel(
    const ushort* __restrict__ WdecT,   // [FDICT][DIM] bf16
    const float* __restrict__ sel_val,
    const int* __restrict__ sel_idx,
    const float* __restrict__ bdec,
    float* __restrict__ out)
{
    const int row = blockIdx.x;
    const int tid = threadIdx.x;
    __shared__ float vv[KSEL];
    __shared__ int   ff[KSEL];
    if (tid < KSEL) {
        vv[tid] = sel_val[row * KSEL + tid];
        ff[tid] = sel_idx[row * KSEL + tid];
    }
    __syncthreads();
    const int d0 = tid * 8;
    float acc[8];
    {
        float4 b0 = *(const float4*)(bdec + d0);
        float4 b1 = *(const float4*)(bdec + d0 + 4);
        acc[0] = b0.x; acc[1] = b0.y; acc[2] = b0.z; acc[3] = b0.w;
        acc[4] = b1.x; acc[5] = b1.y; acc[6] = b1.z; acc[7] = b1.w;
    }
    for (int k = 0; k < KSEL; ++k) {
        const int f = ff[k];
        if ((unsigned)f >= (unsigned)FDICT) continue;   // poison-safety guard
        const float v = vv[k];
        union { ushort s[8]; bf16x8 w; } u;
        u.w = *(const bf16x8*)(WdecT + (size_t)f * DIM + d0);
#pragma unroll
        for (int j = 0; j < 8; ++j)
            acc[j] = fmaf(v, bf16_to_f32(u.s[j]), acc[j]);
    }
    float* orow = out + (size_t)row * DIM + d0;
    float4 o0 = {acc[0], acc[1], acc[2], acc[3]};
    float4 o1 = {acc[4], acc[5], acc[6], acc[7]};
    *(float4*)(orow + 0) = o0;
    *(float4*)(orow + 4) = o1;
}

// ======================= launch =======================
extern "C" void kernel_launch(void* const* d_in, const int* in_sizes, int n_in,
                              void* d_out, int out_size, void* d_ws, size_t ws_size,
                              hipStream_t stream)
{
    const float* x    = (const float*)d_in[0];
    const float* Wenc = (const float*)d_in[1];
    const float* benc = (const float*)d_in[2];
    const float* Wdec = (const float*)d_in[3];
    const float* bdec = (const float*)d_in[4];
    (void)in_sizes; (void)n_in; (void)out_size; (void)ws_size;
    float* out = (float*)d_out;

    char* ws = (char*)d_ws;
    size_t off = 0;
    float*  cand_val = (float*)(ws + off);  off += (size_t)B_ROWS * CAP * 4;   // 12.6 MB
    int*    cand_idx = (int*)(ws + off);    off += (size_t)B_ROWS * CAP * 4;   // 12.6 MB
    int*    cand_cnt = (int*)(ws + off);    off += (size_t)B_ROWS * 4;
    float*  Tthr     = (float*)(ws + off);  off += (size_t)B_ROWS * 4;
    float*  wsum     = (float*)(ws + off);  off += 256;
    ushort* x_bf16   = (ushort*)(ws + off); off += (size_t)B_ROWS * DIM * 2;   // 8 MB
    float*  run_val  = (float*)(ws + off);  off += (size_t)B_ROWS * TOPC * 4;
    int*    run_idx  = (int*)(ws + off);    off += (size_t)B_ROWS * TOPC * 4;
    float*  sel_val  = (float*)(ws + off);  off += (size_t)B_ROWS * KSEL * 4;
    int*    sel_idx  = (int*)(ws + off);    off += (size_t)B_ROWS * KSEL * 4;
    char*   big      = ws + off;            // 128 MB: wenc_bf16, then WdecT

    zero_kernel<<<(B_ROWS + 255) / 256, 256, 0, stream>>>(cand_cnt, wsum);
    wstat_kernel<<<8, 256, 0, stream>>>(Wenc, wsum);
    rownorm_conv_kernel<<<B_ROWS, 256, 0, stream>>>(x, wsum, Tthr, x_bf16);

    ushort* wenc_bf = (ushort*)big;
    conv_bf16_kernel<<<(int)(((size_t)FDICT * DIM) / (256 * 8)), 256, 0, stream>>>(
        Wenc, wenc_bf);
    enc_gemm_cand<<<(B_ROWS / GM) * (FDICT / GN), 512, 0, stream>>>(
        x_bf16, wenc_bf, benc, Tthr, cand_val, cand_idx, cand_cnt);

    select_kernel<<<B_ROWS, 256, 0, stream>>>(cand_val, cand_idx, cand_cnt,
                                              run_val, run_idx);
    refine_np_kernel<<<B_ROWS / 2, 256, 0, stream>>>(x, Wenc, benc,
                                                     run_val, run_idx,
                                                     sel_val, sel_idx);

    ushort* WdecT = (ushort*)big;   // reuse: encode phase done
    transpose_wdec_bf16<<<dim3(FDICT / 64, DIM / 64), 256, 0, stream>>>(Wdec, WdecT);
    decode_full_kernel<<<B_ROWS, 256, 0, stream>>>(WdecT, sel_val, sel_idx, bdec, out);
}